// Round 6
// baseline (358.277 us; speedup 1.0000x reference)
//
#include <hip/hip_runtime.h>

#define NCL 20000
#define DIN 128
#define HID 2048
#define SEVN 2000
#define TPM 0.1f
#define ENTC 0.01f

#define RG 79               // 256-clause groups per event row (79*256 >= 20000)
#define NJOBS (SEVN * RG)   // 158000 pack jobs (one wave-group each)
#define LASTJOB (NJOBS - 1)
#define SPAD 2048

// workspace byte offsets (all 256-aligned)
#define WS_B2K   0
#define WS_W2K   256                 // 8 KB -> 8448
#define WS_LOGIT 8448                // 20000*4 = 80000 -> 88448
#define WS_CDATA 89600               // 20000*16 = 320000 -> 409600
#define WS_BSTG  409600              // 128*2048*2 = 524288 -> 933888
#define WS_PACK  933888              // 158000*8*4 = 5056000 -> 5989888
#define WS_PART  5989888             // 79*5*2048*4 = 3235840 -> 9225728

#define NB_PACK 2048
#define NB_SB   128
#define NB_WK   513

typedef __attribute__((ext_vector_type(8))) short short8;
typedef __attribute__((ext_vector_type(4))) float f32x4;

static __device__ __forceinline__ unsigned short f2bf(float f) {
    unsigned u = __float_as_uint(f);
    u += 0x7FFFu + ((u >> 16) & 1u);     // round-to-nearest-even
    return (unsigned short)(u >> 16);
}
static __device__ __forceinline__ unsigned pck(unsigned short a, unsigned short b) {
    return (unsigned)a | ((unsigned)b << 16);
}

// ---------- K1: fused streamer: uint4-ballot mask pack + stageB + w2k ----------
// pack layout: job = s*RG + gr covers clauses [gr*256, gr*256+256) of event s.
// lane l loads ints 4l..4l+3; ballot k over component k. words[2k+half] = half of ballot k.
// decode: int-in-group = 128*half + 4*bit + k.
__global__ __launch_bounds__(256) void k_stream(const unsigned* __restrict__ mask,
                                                unsigned* __restrict__ packed,
                                                const float* __restrict__ W1,
                                                unsigned short* __restrict__ bst,
                                                const float* __restrict__ W2,
                                                const float* __restrict__ b2,
                                                const float* __restrict__ key,
                                                float* __restrict__ w2k,
                                                float* __restrict__ b2k) {
    int b = blockIdx.x;
    int t = threadIdx.x;

    if (b < NB_PACK) {
        int lane = t & 63;
        int wv   = b * 4 + (t >> 6);
        for (int job = wv; job < NJOBS; job += NB_PACK * 4) {
            int s  = job / RG;
            int gr = job - s * RG;
            const unsigned* gp = mask + (size_t)s * NCL + gr * 256;
            int off = 4 * lane;
            if (job == LASTJOB && lane >= 8) off = 0;   // avoid OOB read past array end
            uint4 m = *(const uint4*)(gp + off);
            unsigned long long B0 = __ballot(m.x != 0);
            unsigned long long B1 = __ballot(m.y != 0);
            unsigned long long B2 = __ballot(m.z != 0);
            unsigned long long B3 = __ballot(m.w != 0);
            if (lane < 8) {
                int k = lane >> 1;
                unsigned long long Bk = (k == 0) ? B0 : (k == 1) ? B1 : (k == 2) ? B2 : B3;
                unsigned v = (lane & 1) ? (unsigned)(Bk >> 32) : (unsigned)Bk;
                packed[(size_t)job * 8 + lane] = v;
            }
        }
        return;
    }
    b -= NB_PACK;

    if (b < NB_SB) {
        // ---- stage W1 -> bf16 B-frag ----
        int g = b * 256 + t;
        int l = g & 63, c = (g >> 6) & 3, ct = g >> 8;
        int col = ct * 16 + (l & 15);
        int kb  = c * 32 + (l >> 4) * 8;
        unsigned short v[8];
        #pragma unroll
        for (int j = 0; j < 8; ++j) v[j] = f2bf(W1[(size_t)(kb + j) * HID + col]);
        uint4 o;
        o.x = pck(v[0], v[1]); o.y = pck(v[2], v[3]);
        o.z = pck(v[4], v[5]); o.w = pck(v[6], v[7]);
        ((uint4*)bst)[g] = o;
        return;
    }
    b -= NB_SB;

    // ---- w2k = W2 @ key; b2k = b2 . key ----
    {
        int wid  = b * 4 + (t >> 6);
        int lane = t & 63;
        const float4* key4 = (const float4*)key;
        float acc = 0.f;
        if (wid <= HID) {
            const float4* row4 = (const float4*)((wid < HID) ? (W2 + (size_t)wid * 2048) : b2);
            #pragma unroll
            for (int it = 0; it < 8; ++it) {
                int idx = it * 64 + lane;
                float4 a = row4[idx], k4 = key4[idx];
                acc += a.x * k4.x + a.y * k4.y + a.z * k4.z + a.w * k4.w;
            }
        }
        #pragma unroll
        for (int m = 1; m < 64; m <<= 1) acc += __shfl_xor(acc, m);
        if (lane == 0 && wid < HID) w2k[wid] = acc;
        if (lane == 0 && wid == HID) *b2k = acc;
    }
}

// ---------- K2: logits = relu(fv@W1+b1)@w2k + b2k; fv loaded direct; fused clause epi ----------
// 625 blocks x 256 thr (4 waves). Block owns 32 rows; wave w owns ct in [w*32, w*32+32).
__global__ __launch_bounds__(256) void k_gemm(const float* __restrict__ fv,
                                              const unsigned short* __restrict__ bst,
                                              const float* __restrict__ b1,
                                              const float* __restrict__ w2k,
                                              const float* __restrict__ b2k,
                                              const int* __restrict__ good,
                                              float* __restrict__ logits,
                                              float4* __restrict__ cd) {
    int blk = blockIdx.x;
    int tid = threadIdx.x;
    int w = tid >> 6, l = tid & 63;
    int colg = l & 15, kg = l >> 4;
    int r0 = blk * 32;

    const short8* B8 = (const short8*)bst;

    short8 afrag[2][4];
    #pragma unroll
    for (int s = 0; s < 2; ++s) {
        const float* rp = fv + (size_t)(r0 + s * 16 + (l & 15)) * DIN + kg * 8;
        #pragma unroll
        for (int c = 0; c < 4; ++c) {
            float4 f0 = *(const float4*)(rp + c * 32);
            float4 f1 = *(const float4*)(rp + c * 32 + 4);
            union { short8 sv; uint4 u; } tmp;
            tmp.u.x = pck(f2bf(f0.x), f2bf(f0.y));
            tmp.u.y = pck(f2bf(f0.z), f2bf(f0.w));
            tmp.u.z = pck(f2bf(f1.x), f2bf(f1.y));
            tmp.u.w = pck(f2bf(f1.z), f2bf(f1.w));
            afrag[s][c] = tmp.sv;
        }
    }

    float acc[2][4];
    #pragma unroll
    for (int s = 0; s < 2; ++s)
        #pragma unroll
        for (int r = 0; r < 4; ++r) acc[s][r] = 0.f;

    int ct0 = w * 32;
    for (int t = 0; t < 32; ++t) {
        int ct = ct0 + t;
        short8 bfr[4];
        #pragma unroll
        for (int c = 0; c < 4; ++c) bfr[c] = B8[((ct * 4 + c) << 6) + l];
        int col = ct * 16 + colg;
        float b1v = b1[col];
        float wkv = w2k[col];
        #pragma unroll
        for (int s = 0; s < 2; ++s) {
            f32x4 d = {0.f, 0.f, 0.f, 0.f};
            #pragma unroll
            for (int c = 0; c < 4; ++c)
                d = __builtin_amdgcn_mfma_f32_16x16x32_bf16(afrag[s][c], bfr[c], d, 0, 0, 0);
            #pragma unroll
            for (int r = 0; r < 4; ++r) {
                float h = d[r] + b1v;
                h = h > 0.f ? h : 0.f;
                acc[s][r] += h * wkv;
            }
        }
    }

    __shared__ float red[4][32];
    #pragma unroll
    for (int s = 0; s < 2; ++s) {
        #pragma unroll
        for (int r = 0; r < 4; ++r) {
            float a = acc[s][r];
            a += __shfl_xor(a, 1);
            a += __shfl_xor(a, 2);
            a += __shfl_xor(a, 4);
            a += __shfl_xor(a, 8);
            if (colg == 0) red[w][s * 16 + kg * 4 + r] = a;
        }
    }
    __syncthreads();
    if (tid < 32) {
        float sum = *b2k;
        #pragma unroll
        for (int ww = 0; ww < 4; ++ww) sum += red[ww][tid];
        int row = r0 + tid;
        logits[row] = sum;
        float e = expf(sum);                 // logits O(+-6): fp32 exp safe
        bool g = good[row] != 0;
        cd[row] = make_float4(e, e * sum, g ? sum : 0.f, g ? 1.f : 0.f);
    }
}

// ---------- K3: events — thread=event, one 256-clause group per block-column ----------
__global__ __launch_bounds__(256) void k_events(const unsigned* __restrict__ packed,
                                                const float4* __restrict__ cd,
                                                float* __restrict__ part) {
    int gr = blockIdx.x >> 3;                // 0..78
    int eg = blockIdx.x & 7;                 // 0..7
    int s  = eg * 256 + threadIdx.x;         // 0..2047
    float Z = 0.f, X = 0.f, cnt = 0.f, ng = 0.f, sg = 0.f;
    if (s < SEVN) {
        const unsigned* wp = packed + ((size_t)s * RG + gr) * 8;
        unsigned wv[8];
        #pragma unroll
        for (int j = 0; j < 8; ++j) wv[j] = wp[j];
        int cbase = gr * 256;
        if (gr < RG - 1) {
            #pragma unroll
            for (int k = 0; k < 4; ++k) {
                #pragma unroll
                for (int half = 0; half < 2; ++half) {
                    unsigned word = wv[2 * k + half];
                    int cb = cbase + 128 * half + k;
                    #pragma unroll
                    for (int b = 0; b < 32; ++b) {
                        float4 c = cd[cb + 4 * b];         // wave-uniform
                        float m = (float)((word >> b) & 1u);
                        Z   += m * c.x;
                        X   += m * c.y;
                        sg  += m * c.z;
                        ng  += m * c.w;
                        cnt += m;
                    }
                }
            }
        } else {
            // partial group: clauses 19968..19999 -> half=0, b<8, all k
            #pragma unroll
            for (int k = 0; k < 4; ++k) {
                unsigned word = wv[2 * k];
                int cb = cbase + k;
                #pragma unroll
                for (int b = 0; b < 8; ++b) {
                    float4 c = cd[cb + 4 * b];
                    float m = (float)((word >> b) & 1u);
                    Z   += m * c.x;
                    X   += m * c.y;
                    sg  += m * c.z;
                    ng  += m * c.w;
                    cnt += m;
                }
            }
        }
    }
    float* pp = part + (size_t)gr * 5 * SPAD;
    pp[0 * SPAD + s] = Z;
    pp[1 * SPAD + s] = X;
    pp[2 * SPAD + s] = cnt;
    pp[3 * SPAD + s] = ng;
    pp[4 * SPAD + s] = sg;
}

// ---------- K4: final reduction + epilogue ----------
__global__ __launch_bounds__(256) void k_final(const float* __restrict__ part,
                                               const float* __restrict__ logits,
                                               const float* __restrict__ times,
                                               const int* __restrict__ sel,
                                               float* __restrict__ out) {
    int s = blockIdx.x * 256 + threadIdx.x;  // 0..2047
    bool live = s < SEVN;
    float Z = 0.f, X = 0.f, cnt = 0.f, ng = 0.f, sg = 0.f;
    if (live) {
        for (int c = 0; c < RG; ++c) {
            const float* pp = part + (size_t)c * 5 * SPAD;
            Z   += pp[0 * SPAD + s];
            X   += pp[1 * SPAD + s];
            cnt += pp[2 * SPAD + s];
            ng  += pp[3 * SPAD + s];
            sg  += pp[4 * SPAD + s];
        }
    }
    float gl = 0.f, ngs = 0.f, tl = 0.f, tv = 0.f, en = 0.f;
    if (live) {
        float L = logf(Z);
        if (ng > 0.5f) { gl = L - sg / ng; ngs = 1.f; }
        float tm = times[s];
        tl = TPM * tm * (logits[sel[s]] - L);
        tv = tm;
        en = ENTC * ((X / Z - L) / logf(cnt));
    }
    #pragma unroll
    for (int m = 1; m < 64; m <<= 1) {
        gl  += __shfl_xor(gl, m);
        ngs += __shfl_xor(ngs, m);
        tl  += __shfl_xor(tl, m);
        tv  += __shfl_xor(tv, m);
        en  += __shfl_xor(en, m);
    }
    if ((threadIdx.x & 63) == 0) {
        atomicAdd(out + 0, gl);
        atomicAdd(out + 1, ngs);
        atomicAdd(out + 2, tl);
        atomicAdd(out + 3, tv);
        atomicAdd(out + 4, en);
    }
    if (s == 0) out[5] = (float)SEVN;
}

extern "C" void kernel_launch(void* const* d_in, const int* in_sizes, int n_in,
                              void* d_out, int out_size, void* d_ws, size_t ws_size,
                              hipStream_t stream) {
    const float* fv    = (const float*)d_in[0];
    const float* W1    = (const float*)d_in[1];
    const float* b1    = (const float*)d_in[2];
    const float* W2    = (const float*)d_in[3];
    const float* b2    = (const float*)d_in[4];
    const float* key   = (const float*)d_in[5];
    const float* times = (const float*)d_in[6];
    const unsigned* mask = (const unsigned*)d_in[7];   // bool -> int32
    const int* good    = (const int*)d_in[8];          // bool -> int32
    const int* sel     = (const int*)d_in[9];
    float* out = (float*)d_out;
    char* ws = (char*)d_ws;

    float* w2k    = (float*)(ws + WS_W2K);
    float* b2k    = (float*)(ws + WS_B2K);
    float* logits = (float*)(ws + WS_LOGIT);
    float4* cdata = (float4*)(ws + WS_CDATA);
    unsigned short* bst = (unsigned short*)(ws + WS_BSTG);
    unsigned* packed = (unsigned*)(ws + WS_PACK);
    float* part   = (float*)(ws + WS_PART);

    hipMemsetAsync(d_out, 0, 6 * sizeof(float), stream);
    k_stream<<<NB_PACK + NB_SB + NB_WK, 256, 0, stream>>>(
        mask, packed, W1, bst, W2, b2, key, w2k, b2k);
    k_gemm <<<NCL / 32, 256, 0, stream>>>(fv, bst, b1, w2k, b2k, good, logits, cdata);
    k_events<<<RG * 8, 256, 0, stream>>>(packed, cdata, part);
    k_final<<<SPAD / 256, 256, 0, stream>>>(part, logits, times, sel, out);
}